// Round 1
// baseline (7073.702 us; speedup 1.0000x reference)
//
#include <hip/hip_runtime.h>
#include <hip/hip_fp16.h>

#define DEVINL __device__ __forceinline__

constexpr int B = 256, S = 512;
constexpr int H0 = 64, H1 = 128, H2 = 256;

typedef _Float16 h2v __attribute__((ext_vector_type(2)));

DEVINL h2v as_h2(unsigned u) { union { unsigned u; h2v h; } x; x.u = u; return x.h; }
DEVINL float fexp2(float x) { return __builtin_amdgcn_exp2f(x); }
DEVINL float frcp(float x) { return __builtin_amdgcn_rcpf(x); }
// sigmoid(x) = 1/(1+2^(-x*log2e))
DEVINL float fsig(float x) { return frcp(1.f + fexp2(-1.44269504088896f * x)); }
// tanh(x) = 1 - 2/(1+2^(x*2*log2e))   (exact at +-inf, no overflow issues)
DEVINL float ftanh_(float x) { return 1.f - 2.f * frcp(1.f + fexp2(2.88539008177793f * x)); }
DEVINL float fdot2(unsigned a, unsigned b, float c) {
  return __builtin_amdgcn_fdot2(as_h2(a), as_h2(b), c, false);
}

// Pack Whh [4H][H] fp32 (torch gate order i,f,g,o) into fp16 k-pair layout:
// wt[kp*H + t] = uint4{ q0:(half2 W[q*H+t][2kp],W[q*H+t][2kp+1]), q1.., q2.., q3.. }
__global__ __launch_bounds__(256) void pack_whh(const float* __restrict__ w,
                                                uint4* __restrict__ wt, int H) {
  int i = blockIdx.x * 256 + threadIdx.x;
  int tot = (H / 2) * H;
  if (i >= tot) return;
  int t = i % H, kp = i / H;
  unsigned r[4];
#pragma unroll
  for (int q = 0; q < 4; ++q) {
    float f0 = w[(size_t)(q * H + t) * H + 2 * kp];
    float f1 = w[(size_t)(q * H + t) * H + 2 * kp + 1];
    unsigned lo = __half_as_ushort(__float2half_rn(f0));
    unsigned hi = __half_as_ushort(__float2half_rn(f1));
    r[q] = (hi << 16) | lo;
  }
  uint4 o4; o4.x = r[0]; o4.y = r[1]; o4.z = r[2]; o4.w = r[3];
  wt[i] = o4;
}

// pre[b*Sc+tl][j] = sum_k x[b][t0+tl][k] * Wih[j][k] + bih[j] + bhh[j]
// 64x64 tile, fp32, XOR-swizzled LDS (float4 granules) to avoid bank conflicts.
template <int K>
__global__ __launch_bounds__(256) void ingemm(const float* __restrict__ x,
    const float* __restrict__ wih, const float* __restrict__ bih,
    const float* __restrict__ bhh, float* __restrict__ pre,
    int N, int Sc, int t0) {
  constexpr int KT = (K < 64) ? K : 64;
  constexpr int KTB = KT / 4;
  __shared__ float4 As[64 * KTB];
  __shared__ float4 Bs[64 * KTB];
  const int tid = threadIdx.x;
  const int rp0 = blockIdx.x * 64;
  const int n0 = blockIdx.y * 64;
  const int tn = tid & 15, tm = tid >> 4;
  float acc[4][4] = {};
  for (int ks = 0; ks < K; ks += KT) {
    for (int i = tid; i < 64 * KTB; i += 256) {
      int rr = i / KTB, kq = i % KTB;
      int rp = rp0 + rr;
      int b = rp / Sc, tl = rp - b * Sc;
      const float* srcx = x + (size_t)(b * S + t0 + tl) * K + ks + 4 * kq;
      As[rr * KTB + (kq ^ ((rr >> 2) & 7))] = *reinterpret_cast<const float4*>(srcx);
      const float* srcw = wih + (size_t)(n0 + rr) * K + ks + 4 * kq;
      Bs[rr * KTB + (kq ^ ((rr >> 2) & 7))] = *reinterpret_cast<const float4*>(srcw);
    }
    __syncthreads();
#pragma unroll 8
    for (int kb = 0; kb < KTB; ++kb) {
      float4 a[4], bb[4];
#pragma unroll
      for (int i2 = 0; i2 < 4; ++i2) a[i2] = As[(4 * tm + i2) * KTB + (kb ^ (tm & 7))];
#pragma unroll
      for (int j = 0; j < 4; ++j) bb[j] = Bs[(4 * tn + j) * KTB + (kb ^ (tn & 7))];
#pragma unroll
      for (int i2 = 0; i2 < 4; ++i2)
#pragma unroll
        for (int j = 0; j < 4; ++j) {
          acc[i2][j] += a[i2].x * bb[j].x;
          acc[i2][j] += a[i2].y * bb[j].y;
          acc[i2][j] += a[i2].z * bb[j].z;
          acc[i2][j] += a[i2].w * bb[j].w;
        }
    }
    __syncthreads();
  }
  float4 bi = *reinterpret_cast<const float4*>(bih + n0 + 4 * tn);
  float4 bh = *reinterpret_cast<const float4*>(bhh + n0 + 4 * tn);
  float bx = bi.x + bh.x, by = bi.y + bh.y, bz = bi.z + bh.z, bw = bi.w + bh.w;
#pragma unroll
  for (int i2 = 0; i2 < 4; ++i2) {
    int rp = rp0 + 4 * tm + i2;
    float4 v; v.x = acc[i2][0] + bx; v.y = acc[i2][1] + by;
    v.z = acc[i2][2] + bz; v.w = acc[i2][3] + bw;
    *reinterpret_cast<float4*>(pre + (size_t)rp * N + n0 + 4 * tn) = v;
  }
}

#define DOT16()                                        \
  do {                                                 \
    acc[0][0] = fdot2(w.x, hh.x, acc[0][0]);           \
    acc[0][1] = fdot2(w.x, hh.y, acc[0][1]);           \
    acc[0][2] = fdot2(w.x, hh.z, acc[0][2]);           \
    acc[0][3] = fdot2(w.x, hh.w, acc[0][3]);           \
    acc[1][0] = fdot2(w.y, hh.x, acc[1][0]);           \
    acc[1][1] = fdot2(w.y, hh.y, acc[1][1]);           \
    acc[1][2] = fdot2(w.y, hh.z, acc[1][2]);           \
    acc[1][3] = fdot2(w.y, hh.w, acc[1][3]);           \
    acc[2][0] = fdot2(w.z, hh.x, acc[2][0]);           \
    acc[2][1] = fdot2(w.z, hh.y, acc[2][1]);           \
    acc[2][2] = fdot2(w.z, hh.z, acc[2][2]);           \
    acc[2][3] = fdot2(w.z, hh.w, acc[2][3]);           \
    acc[3][0] = fdot2(w.w, hh.x, acc[3][0]);           \
    acc[3][1] = fdot2(w.w, hh.y, acc[3][1]);           \
    acc[3][2] = fdot2(w.w, hh.z, acc[3][2]);           \
    acc[3][3] = fdot2(w.w, hh.w, acc[3][3]);           \
  } while (0)

// Recurrent scan over one time-chunk. 64 WGs x 4 batch rows, 256 threads.
// thread = (kap = tid/H k-split group, t = tid%H output channel).
// Weights: first KPL k-pairs in LDS, rest streamed from L2 (fp16, uint4/thread/kp).
// h kept in LDS as packed half2 pairs (broadcast reads), c in registers.
template <int H, int KSPLIT, int KPL, bool L2L>
__global__ __launch_bounds__(256) void scan(const uint4* __restrict__ wt,
    const float* __restrict__ pre, float* __restrict__ xout,
    float* __restrict__ out, const float* __restrict__ wl,
    const float* __restrict__ blp, float* __restrict__ sth,
    float* __restrict__ stc, int Sc, int t0, int first) {
  constexpr int KP = H / 2;
  constexpr int KPC = KP / KSPLIT;
  constexpr int N = 4 * H;
  __shared__ uint4 wlds[KPL * H];
  __shared__ uint4 h2b[KP];
  __shared__ float red[(KSPLIT > 1) ? (KSPLIT - 1) * 16 * H : 1];
  __shared__ float hs[L2L ? 4 * H : 4];
  __shared__ float wls[L2L ? H : 4];
  const int tid = threadIdx.x;
  const int t = tid % H;
  const int kap = tid / H;
  const int b0 = blockIdx.x * 4;

  for (int i = tid; i < KPL * H; i += 256) wlds[i] = wt[i];
  if (L2L)
    for (int i = tid; i < H; i += 256) wls[i] = wl[i];

  float cst[4] = {}, hst[4] = {};
  if (kap == 0) {
#pragma unroll
    for (int r = 0; r < 4; ++r) {
      float hv = 0.f, cv = 0.f;
      if (!first) {
        hv = sth[(size_t)(b0 + r) * H + t];
        cv = stc[(size_t)(b0 + r) * H + t];
      }
      hst[r] = hv; cst[r] = cv;
      reinterpret_cast<__half*>(&h2b[t >> 1])[(r << 1) | (t & 1)] = __float2half_rn(hv);
      if (L2L) hs[r * H + t] = hv;
    }
  }
  __syncthreads();
  const float bl0 = L2L ? blp[0] : 0.f;
  const int kp0 = kap * KPC, kp1 = kp0 + KPC;
  const int kL = (kp1 < KPL) ? kp1 : KPL;       // LDS segment end
  const int kG = (kp0 > KPL) ? kp0 : KPL;       // global segment start

  for (int tl = 0; tl < Sc; ++tl) {
    float pg[4][4];
    if (kap == 0) {
#pragma unroll
      for (int r = 0; r < 4; ++r) {
        const float* pp = pre + ((size_t)(b0 + r) * Sc + tl) * N + t;
#pragma unroll
        for (int q = 0; q < 4; ++q) pg[q][r] = pp[q * H];
      }
    }
    float acc[4][4] = {};
#pragma unroll 8
    for (int kp = kp0; kp < kL; ++kp) {
      uint4 w = wlds[kp * H + t];
      uint4 hh = h2b[kp];
      DOT16();
    }
#pragma unroll 8
    for (int kp = kG; kp < kp1; ++kp) {
      uint4 w = wt[(size_t)kp * H + t];
      uint4 hh = h2b[kp];
      DOT16();
    }
    __syncthreads();  // all h2b reads of this step done
    if (KSPLIT > 1) {
      if (kap > 0) {
        float* rp = red + (size_t)(kap - 1) * 16 * H + t;
#pragma unroll
        for (int q = 0; q < 4; ++q)
#pragma unroll
          for (int r = 0; r < 4; ++r) rp[(q * 4 + r) * H] = acc[q][r];
      }
      __syncthreads();
    }
    if (kap == 0) {
      if (KSPLIT > 1) {
#pragma unroll
        for (int kk = 0; kk < KSPLIT - 1; ++kk) {
          const float* rp = red + (size_t)kk * 16 * H + t;
#pragma unroll
          for (int q = 0; q < 4; ++q)
#pragma unroll
            for (int r = 0; r < 4; ++r) acc[q][r] += rp[(q * 4 + r) * H];
        }
      }
#pragma unroll
      for (int r = 0; r < 4; ++r) {
        float gi = fsig(pg[0][r] + acc[0][r]);
        float gf = fsig(pg[1][r] + acc[1][r]);
        float gg = ftanh_(pg[2][r] + acc[2][r]);
        float go = fsig(pg[3][r] + acc[3][r]);
        float cv = gf * cst[r] + gi * gg;
        cst[r] = cv;
        float hv = go * ftanh_(cv);
        hst[r] = hv;
        reinterpret_cast<__half*>(&h2b[t >> 1])[(r << 1) | (t & 1)] = __float2half_rn(hv);
        if (L2L) hs[r * H + t] = hv;
        else xout[((size_t)(b0 + r) * S + (t0 + tl)) * H + t] = hv;
      }
    }
    __syncthreads();  // h2b/hs ready
    if (L2L) {
      int r = tid >> 6, l = tid & 63;
      float s = hs[r * H + l] * wls[l] + hs[r * H + l + 64] * wls[l + 64] +
                hs[r * H + l + 128] * wls[l + 128] + hs[r * H + l + 192] * wls[l + 192];
#pragma unroll
      for (int off = 32; off; off >>= 1) s += __shfl_down(s, off);
      if (l == 0) out[(size_t)(b0 + r) * S + (t0 + tl)] = ftanh_(s + bl0);
    }
  }
  if (kap == 0) {
#pragma unroll
    for (int r = 0; r < 4; ++r) {
      sth[(size_t)(b0 + r) * H + t] = hst[r];
      stc[(size_t)(b0 + r) * H + t] = cst[r];
    }
  }
}

extern "C" void kernel_launch(void* const* d_in, const int* in_sizes, int n_in,
                              void* d_out, int out_size, void* d_ws, size_t ws_size,
                              hipStream_t stream) {
  (void)in_sizes; (void)n_in; (void)out_size;
  const float* noise = (const float*)d_in[0];
  const float* Wih0 = (const float*)d_in[1];
  const float* Whh0 = (const float*)d_in[2];
  const float* bih0 = (const float*)d_in[3];
  const float* bhh0 = (const float*)d_in[4];
  const float* Wih1 = (const float*)d_in[5];
  const float* Whh1 = (const float*)d_in[6];
  const float* bih1 = (const float*)d_in[7];
  const float* bhh1 = (const float*)d_in[8];
  const float* Wih2 = (const float*)d_in[9];
  const float* Whh2 = (const float*)d_in[10];
  const float* bih2 = (const float*)d_in[11];
  const float* bhh2 = (const float*)d_in[12];
  const float* Wl = (const float*)d_in[13];
  const float* bl = (const float*)d_in[14];
  float* out = (float*)d_out;

  char* p = (char*)d_ws;
  auto alloc = [&](size_t bytes) {
    char* r = p;
    p += (bytes + 255) & ~(size_t)255;
    return r;
  };
  uint4* wt0 = (uint4*)alloc((size_t)(H0 / 2) * H0 * 16);
  uint4* wt1 = (uint4*)alloc((size_t)(H1 / 2) * H1 * 16);
  uint4* wt2 = (uint4*)alloc((size_t)(H2 / 2) * H2 * 16);
  float* sh0 = (float*)alloc((size_t)B * H0 * 4);
  float* sc0 = (float*)alloc((size_t)B * H0 * 4);
  float* sh1 = (float*)alloc((size_t)B * H1 * 4);
  float* sc1 = (float*)alloc((size_t)B * H1 * 4);
  float* sh2 = (float*)alloc((size_t)B * H2 * 4);
  float* sc2 = (float*)alloc((size_t)B * H2 * 4);
  float* x1 = (float*)alloc((size_t)B * S * H0 * 4);
  float* x2 = (float*)alloc((size_t)B * S * H1 * 4);
  size_t fixed = (size_t)(p - (char*)d_ws);
  int Sc = 128;  // time-chunk: bounds pre-buffer (Sc MiB) and keeps it L3-resident
  while (Sc > 16 && fixed + (size_t)B * Sc * 1024 * 4 > ws_size) Sc >>= 1;
  float* pre = (float*)alloc((size_t)B * Sc * 1024 * 4);

  pack_whh<<<((H0 / 2) * H0 + 255) / 256, 256, 0, stream>>>(Whh0, wt0, H0);
  pack_whh<<<((H1 / 2) * H1 + 255) / 256, 256, 0, stream>>>(Whh1, wt1, H1);
  pack_whh<<<((H2 / 2) * H2 + 255) / 256, 256, 0, stream>>>(Whh2, wt2, H2);

  for (int c = 0; c < S / Sc; ++c) {
    int t0 = c * Sc;
    int mt = B * Sc / 64;
    ingemm<32><<<dim3(mt, 4), 256, 0, stream>>>(noise, Wih0, bih0, bhh0, pre, 256, Sc, t0);
    scan<64, 4, 32, false><<<64, 256, 0, stream>>>(wt0, pre, x1, nullptr, nullptr,
                                                   nullptr, sh0, sc0, Sc, t0, c == 0);
    ingemm<64><<<dim3(mt, 8), 256, 0, stream>>>(x1, Wih1, bih1, bhh1, pre, 512, Sc, t0);
    scan<128, 2, 26, false><<<64, 256, 0, stream>>>(wt1, pre, x2, nullptr, nullptr,
                                                    nullptr, sh1, sc1, Sc, t0, c == 0);
    ingemm<128><<<dim3(mt, 16), 256, 0, stream>>>(x2, Wih2, bih2, bhh2, pre, 1024, Sc, t0);
    scan<256, 1, 13, true><<<64, 256, 0, stream>>>(wt2, pre, nullptr, out, Wl, bl,
                                                   sh2, sc2, Sc, t0, c == 0);
  }
}